// Round 8
// baseline (230.652 us; speedup 1.0000x reference)
//
#include <hip/hip_runtime.h>

typedef float f32x4 __attribute__((ext_vector_type(4)));
typedef short short8 __attribute__((ext_vector_type(8)));
typedef unsigned int u32;
typedef unsigned short u16;
typedef u32 u32x2 __attribute__((ext_vector_type(2)));

#define CLL 0.25f                     // landmark self/neighbor coeff (deg=4)
#define CML 0.06019292654288460f      // 0.5/sqrt(69)
#define SELFM 0.014492753623188406f   // 1/69
#define UCS 208                       // ucm col stride BYTES (52 words: 8 bank-starts/16 lanes)

__device__ __forceinline__ u16 f2bf(float x) {
  u32 b = __float_as_uint(x);
  return (u16)((b + 0x7FFFu + ((b >> 16) & 1u)) >> 16);
}
__device__ __forceinline__ u32 cvtpk(float a, float b) {
  u32 r;
  asm("v_cvt_pk_bf16_f32 %0, %1, %2" : "=v"(r) : "v"(a), "v"(b));
  return r;
}

// prep: (a) W mats -> bf16 MFMA B-fragments; (b) BN folded to sc/sh;
//       (c) aggregation matrix A (69x69 ring + master row/col), EXTENDED with
//           column k=80 := 1.0 (rows<69) so u-row 80 carries the per-layer bias
//           through MFMA2. 12 constant bf16 A-fragments (13 nonzero tiles).
__global__ void prep(const float* __restrict__ midW, const float* __restrict__ lastW,
                     const float* __restrict__ bng, const float* __restrict__ bnb,
                     const float* __restrict__ bnm, const float* __restrict__ bnv,
                     u16* __restrict__ frag, float* __restrict__ bns,
                     u16* __restrict__ afr) {
  const int t0 = blockIdx.x * blockDim.x + threadIdx.x;
  const int stride = gridDim.x * blockDim.x;
  for (int u = t0; u < 7 * 4 * 2 * 64; u += stride) {
    const int lane = u & 63;
    const int t = u >> 6;
    const int ks = t & 1;
    const int nt = (t >> 1) & 3;
    const int l = t >> 3;  // 0..6 -> layers 1..7
    const float* W = (l < 6) ? (midW + l * 4096) : lastW;
    const int col = nt * 16 + (lane & 15);
    const int kb = ks * 32 + (lane >> 4) * 8;
    u16* dst = frag + (size_t)u * 8;
#pragma unroll
    for (int j = 0; j < 8; ++j) dst[j] = f2bf(W[(kb + j) * 64 + col]);
  }
  for (int u = t0; u < 7 * 64; u += stride) {
    const int l = u >> 6, f = u & 63;
    const float sc = (float)((double)bng[l * 64 + f] / sqrt((double)bnv[l * 64 + f] + 1e-5));
    bns[l * 128 + f] = sc;
    bns[l * 128 + 64 + f] = bnb[l * 64 + f] - bnm[l * 64 + f] * sc;
  }
  // A-frags: p -> (mt, ks). frag9 (1,2) reused for mt=2 (identical content).
  const int MTs[12] = {0, 1, 2, 4, 1, 2, 3, 4, 0, 1, 3, 4};
  const int KSs[12] = {0, 0, 0, 0, 1, 1, 1, 1, 2, 2, 2, 2};
  for (int u = t0; u < 12 * 64; u += stride) {
    const int p = u >> 6, lane = u & 63;
    const int r = MTs[p] * 16 + (lane & 15);
    const int kb = KSs[p] * 32 + ((lane >> 4) << 3);
    u16* dst = afr + (size_t)u * 8;
#pragma unroll
    for (int j = 0; j < 8; ++j) {
      const int k = kb + j;
      float v = 0.f;
      if (r < 68) {
        if (k < 68) {
          if (k == r || k == (r + 1) % 68 || k == (r + 67) % 68) v = CLL;
        } else if (k == 68) {
          v = CML;
        } else if (k == 80) {
          v = 1.f;  // bias column
        }
      } else if (r == 68) {
        if (k < 68) v = CML;
        else if (k == 68) v = SELFM;
        else if (k == 80) v = 1.f;  // bias column
      }
      dst[j] = f2bf(v);
    }
  }
}

#define SUM4(V) ((V)[0] + (V)[1] + (V)[2] + (V)[3])
#define MAX4(V) fmaxf(fmaxf((V)[0], (V)[1]), fmaxf((V)[2], (V)[3]))
#define MM(A, B, C) __builtin_amdgcn_mfma_f32_16x16x32_bf16(A, B, C, 0, 0, 0)

// MFMA1: u_tile = h @ W  (reads swizzled hb)
#define MP2(HR, MT, T)                                                   \
  {                                                                      \
    const short8 a0 = *(const short8*)&(HR)[(MT) * 1024 + ra0];          \
    const short8 a1 = *(const short8*)&(HR)[(MT) * 1024 + ra1];          \
    f32x4 acc = z4;                                                      \
    acc = MM(a0, b0, acc);                                               \
    acc = MM(a1, b1, acc);                                               \
    T = acc;                                                             \
  }

// u write: 4 consecutive nodes, col-major swizzled, one ds_write_b64
#define UWR(OFF, U)                                                      \
  {                                                                      \
    u32x2 w;                                                             \
    w.x = cvtpk(U[0], U[1]);                                             \
    w.y = cvtpk(U[2], U[3]);                                             \
    *(u32x2*)((char*)ucm + (OFF)) = w;                                   \
  }

// bias row (node 80) of ucm, one u16 per column, written by qg==0 threads
#define BIASROW(B)                                                       \
  if (qg == 0) ucm[c * (UCS / 2) + ((10 ^ e3) << 3)] = f2bf(B);

// epilogue: relu + bn-affine + residual (bias already inside AG via MFMA2)
#define EPI2BN(AG, H, RESID)                                             \
  {                                                                      \
    _Pragma("unroll") for (int e = 0; e < 4; ++e) {                      \
      float v = fmaf(fmaxf(AG[e], 0.f), sc, sh);                         \
      if (RESID) v += H[e];                                              \
      H[e] = v;                                                          \
    }                                                                    \
  }

// bf16 h write into swizzled hb (addresses: 4 precomputed bases + immediates)
#define WPAIR(HW, MT, H)                                                 \
  {                                                                      \
    const u32 pa = cvtpk(H[0], H[1]);                                    \
    const u32 pb = cvtpk(H[2], H[3]);                                    \
    (HW)[(MT) * 1024 + 0 * 64 + wr0] = (u16)pa;                          \
    (HW)[(MT) * 1024 + 1 * 64 + wr1] = (u16)(pa >> 16);                  \
    (HW)[(MT) * 1024 + 2 * 64 + wr2] = (u16)pb;                          \
    (HW)[(MT) * 1024 + 3 * 64 + wr3] = (u16)(pb >> 16);                  \
  }

// MFMA2 + epilogue + h-write for all 5 M-tiles
#define AGG_EPI(HW, RESID, WRITE_H)                                      \
  {                                                                      \
    const short8 ub0 = *(const short8*)((const char*)ucm + urb);         \
    const short8 ub1 = *(const short8*)((const char*)ucm + urb + 64);    \
    const short8 ub2 = *(const short8*)((const char*)ucm + urb + 128);   \
    f32x4 ag;                                                            \
    ag = MM(F8, ub2, MM(F0, ub0, z4));                                   \
    EPI2BN(ag, h0, RESID);                                               \
    if (WRITE_H) WPAIR(HW, 0, h0);                                       \
    ag = MM(F9, ub2, MM(F4, ub1, MM(F1, ub0, z4)));                      \
    EPI2BN(ag, h1, RESID);                                               \
    if (WRITE_H) WPAIR(HW, 1, h1);                                       \
    ag = MM(F9, ub2, MM(F5, ub1, MM(F2, ub0, z4)));                      \
    EPI2BN(ag, h2, RESID);                                               \
    if (WRITE_H) WPAIR(HW, 2, h2);                                       \
    ag = MM(F10, ub2, MM(F6, ub1, z4));                                  \
    EPI2BN(ag, h3, RESID);                                               \
    if (WRITE_H) WPAIR(HW, 3, h3);                                       \
    ag = MM(F11, ub2, MM(F7, ub1, MM(F3, ub0, z4)));                     \
    EPI2BN(ag, h4, RESID);                                               \
    if (WRITE_H) WPAIR(HW, 4, h4);                                       \
  }

__launch_bounds__(256)
__global__ void gcn_fused(
    const float* __restrict__ x,
    const float* __restrict__ cfW, const float* __restrict__ cfb,
    const float* __restrict__ cmb, const float* __restrict__ clb,
    const float* __restrict__ aW1, const float* __restrict__ ab1,
    const float* __restrict__ aW2, const float* __restrict__ ab2,
    const float* __restrict__ f1W, const float* __restrict__ f1b,
    const float* __restrict__ f2W, const float* __restrict__ f2b,
    const u16* __restrict__ frag, const float* __restrict__ bns,
    const u16* __restrict__ afr,
    float* __restrict__ out) {
  __shared__ u16 hb[2][80 * 64];               // bf16 h double-buffer (row-major, swizzled)
  __shared__ __align__(16) u16 ucm[64 * (UCS / 2)];  // u col-major, stride 208 B, blk-swizzled
  __shared__ float xl4[80 * 4];                // staged x, rows 69..79 = 0
  __shared__ float mrow[64];                   // final master h
  __shared__ float gv[192];                    // readout concat [mean|max|master*att]
  __shared__ float part[256];                  // cross-wave partials (att / fc1)

  const int tid = threadIdx.x;
  const int g = blockIdx.x;
  const int lane = tid & 63;
  const int wv = tid >> 6;
  const int p15 = lane & 15;
  const int qg = lane >> 4;
  const int c = wv * 16 + p15;            // this thread's feature column
  const f32x4 z4 = {0.f, 0.f, 0.f, 0.f};

  // hb A-frag read addresses (MFMA1)
  const int rsw = (p15 & 7) << 3;
  const int ra0 = (p15 * 64 + qg * 8) ^ rsw;
  const int ra1 = (p15 * 64 + 32 + qg * 8) ^ rsw;
  // hb write bases
  const int cq = c ^ ((qg & 1) << 5);
  const int wr0 = qg * 256 + cq;
  const int wr1 = qg * 256 + (cq ^ 8);
  const int wr2 = qg * 256 + (cq ^ 16);
  const int wr3 = qg * 256 + (cq ^ 24);
  // ucm addresses: col stride 208 B; 16B-block index XOR-swizzled with (c&3)
  const int e3 = c & 3;
  const int q1 = qg >> 1;
  const int q0 = (qg & 1) << 3;
  const int cb = c * UCS;
  const int uw0 = cb + (((0 + q1) ^ e3) << 4) + q0;   // blk 2*mt + (qg>>1)
  const int uw1 = cb + (((2 + q1) ^ e3) << 4) + q0;
  const int uw2 = cb + (((4 + q1) ^ e3) << 4) + q0;
  const int uw3 = cb + (((6 + q1) ^ e3) << 4) + q0;
  const int uw4 = cb + (((8 + q1) ^ e3) << 4) + q0;
  const int urb = cb + ((qg ^ e3) << 4);              // + 64*ks for ks=0,1,2

  // constant A-fragments (12 x short8, loaded once)
  const u16* ap = afr + (size_t)lane * 8;
  const short8 F0 = *(const short8*)(ap);
  const short8 F1 = *(const short8*)(ap + 512);
  const short8 F2 = *(const short8*)(ap + 1024);
  const short8 F3 = *(const short8*)(ap + 1536);
  const short8 F4 = *(const short8*)(ap + 2048);
  const short8 F5 = *(const short8*)(ap + 2560);
  const short8 F6 = *(const short8*)(ap + 3072);
  const short8 F7 = *(const short8*)(ap + 3584);
  const short8 F8 = *(const short8*)(ap + 4096);
  const short8 F9 = *(const short8*)(ap + 4608);
  const short8 F10 = *(const short8*)(ap + 5120);
  const short8 F11 = *(const short8*)(ap + 5632);

  // prefetch layer-1 W fragments
  const u16* fb1 = frag + ((size_t)(0 * 4 + wv) * 2 * 64 + lane) * 8;
  short8 b0 = *(const short8*)fb1;
  short8 b1 = *(const short8*)(fb1 + 512);

  // zero ucm once (rows 81..95 must stay 0: they feed MFMA2's K=2 step); stage x
  {
    f32x4* ucz = (f32x4*)ucm;
#pragma unroll
    for (int it = 0; it < 4; ++it) {
      const int i = tid + it * 256;
      if (i < 64 * UCS / 16) ucz[i] = z4;
    }
  }
  if (tid < 69)
    *(f32x4*)&xl4[tid * 4] = *(const f32x4*)&x[((size_t)g * 69 + tid) * 4];
  else if (tid < 80)
    *(f32x4*)&xl4[tid * 4] = z4;

  f32x4 h0, h1, h2, h3, h4;

  __syncthreads();

  // ---- layer 0: u = x @ W_first (exact fp32, K=4) -> MFMA2 agg path
  {
    const float w0 = cfW[c], w1 = cfW[64 + c], w2 = cfW[128 + c], w3 = cfW[192 + c];
    f32x4 u0, u1, u2, u3, u4;
#define L0T(MT, T)                                                          \
    { _Pragma("unroll") for (int r = 0; r < 4; ++r) {                       \
        const f32x4 xv = *(const f32x4*)&xl4[(16 * (MT) + 4 * qg + r) * 4]; \
        T[r] = fmaf(xv[0], w0, fmaf(xv[1], w1, fmaf(xv[2], w2, xv[3] * w3))); } }
    L0T(0, u0) L0T(1, u1) L0T(2, u2) L0T(3, u3) L0T(4, u4)
#undef L0T
    BIASROW(cfb[c])
    UWR(uw0, u0) UWR(uw1, u1) UWR(uw2, u2) UWR(uw3, u3) UWR(uw4, u4)
    const float sc = bns[c], sh = bns[64 + c];
    u16* hw = &hb[0][0];
    AGG_EPI(hw, false, true)
  }
  __syncthreads();

  // ---- layers 1..6: MFMA1 (h@W) -> MFMA2 (A@u, bias fused) -> epilogue
#pragma unroll 1
  for (int l = 1; l <= 6; ++l) {
    const u16* fbn = frag + ((size_t)(l * 4 + wv) * 2 * 64 + lane) * 8;
    const short8 nb0 = *(const short8*)fbn;
    const short8 nb1 = *(const short8*)(fbn + 512);
    const float sc = bns[l * 128 + c];
    const float sh = bns[l * 128 + 64 + c];
    const u16* hr = &hb[(l + 1) & 1][0];
    u16* hw = &hb[l & 1][0];
    f32x4 u0, u1, u2, u3, u4;
    MP2(hr, 0, u0) MP2(hr, 1, u1) MP2(hr, 2, u2) MP2(hr, 3, u3) MP2(hr, 4, u4)
    BIASROW(cmb[(l - 1) * 64 + c])
    UWR(uw0, u0) UWR(uw1, u1) UWR(uw2, u2) UWR(uw3, u3) UWR(uw4, u4)
    b0 = nb0;
    b1 = nb1;
    AGG_EPI(hw, true, true)
    __syncthreads();
  }

  // ---- layer 7: MFMA1 -> MFMA2 -> relu only (no bn/resid/h-write)
  {
    const u16* hr = &hb[0][0];
    f32x4 u0, u1, u2, u3, u4;
    MP2(hr, 0, u0) MP2(hr, 1, u1) MP2(hr, 2, u2) MP2(hr, 3, u3) MP2(hr, 4, u4)
    BIASROW(clb[c])
    UWR(uw0, u0) UWR(uw1, u1) UWR(uw2, u2) UWR(uw3, u3) UWR(uw4, u4)
    const float sc = 1.f, sh = 0.f;
    AGG_EPI((u16*)nullptr, false, false)
  }

  // ---- readout: per-col landmark mean/max from registers
  {
    float s = SUM4(h0) + SUM4(h1) + SUM4(h2) + SUM4(h3);
    float mx = fmaxf(fmaxf(MAX4(h0), MAX4(h1)), fmaxf(MAX4(h2), MAX4(h3)));
    if (qg == 0) {  // nodes 64..67 (valid landmarks) live in qg==0's mt=4 run
      s += SUM4(h4);
      mx = fmaxf(mx, MAX4(h4));
    }
    s += __shfl_xor(s, 16, 64);
    s += __shfl_xor(s, 32, 64);
    mx = fmaxf(mx, __shfl_xor(mx, 16, 64));
    mx = fmaxf(mx, __shfl_xor(mx, 32, 64));
    if (qg == 0) {
      gv[c] = s * (1.f / 68.f);
      gv[64 + c] = mx;
    }
    if (qg == 1) mrow[c] = h4[0];  // master h (node 68 = mt4,qg1,reg0)
  }
  __syncthreads();

  // ---- attention gate (distributed over all 4 waves)
  {
    float z = 0.f;
#pragma unroll
    for (int k = 0; k < 16; ++k)
      z = fmaf(mrow[wv * 16 + k], aW1[(wv * 16 + k) * 64 + lane], z);
    part[wv * 64 + lane] = z;
  }
  __syncthreads();
  if (tid < 64) {
    float z = part[tid] + part[64 + tid] + part[128 + tid] + part[192 + tid] + ab1[tid];
    z = fmaxf(z, 0.f);
    float pr = z * aW2[tid];
#pragma unroll
    for (int off = 32; off > 0; off >>= 1) pr += __shfl_xor(pr, off, 64);
    const float att = 1.f / (1.f + expf(-(pr + ab2[0])));
    gv[128 + tid] = mrow[tid] * att;
  }
  __syncthreads();

  // ---- fc1 partials (distributed over all 4 waves)
  {
    float a = 0.f;
#pragma unroll
    for (int i = 0; i < 48; ++i)
      a = fmaf(gv[wv * 48 + i], f1W[(wv * 48 + i) * 64 + lane], a);
    part[wv * 64 + lane] = a;
  }
  __syncthreads();
  if (tid < 64) {
    float a = part[tid] + part[64 + tid] + part[128 + tid] + part[192 + tid] + f1b[tid];
    const float y = fmaxf(a, 0.f);
    float po[7];
#pragma unroll
    for (int o = 0; o < 7; ++o) po[o] = y * f2W[tid * 7 + o];
#pragma unroll
    for (int o = 0; o < 7; ++o)
#pragma unroll
      for (int off = 32; off > 0; off >>= 1) po[o] += __shfl_xor(po[o], off, 64);
    if (tid == 0) {
#pragma unroll
      for (int o = 0; o < 7; ++o) out[(size_t)g * 7 + o] = po[o] + f2b[o];
    }
  }
}

extern "C" void kernel_launch(void* const* d_in, const int* in_sizes, int n_in,
                              void* d_out, int out_size, void* d_ws, size_t ws_size,
                              hipStream_t stream) {
  (void)in_sizes; (void)n_in; (void)ws_size;
  const float* x   = (const float*)d_in[0];
  const float* cfW = (const float*)d_in[4];
  const float* cfb = (const float*)d_in[5];
  const float* cmW = (const float*)d_in[6];
  const float* cmb = (const float*)d_in[7];
  const float* clW = (const float*)d_in[8];
  const float* clb = (const float*)d_in[9];
  const float* bng = (const float*)d_in[10];
  const float* bnb = (const float*)d_in[11];
  const float* bnm = (const float*)d_in[12];
  const float* bnv = (const float*)d_in[13];
  const float* aW1 = (const float*)d_in[14];
  const float* ab1 = (const float*)d_in[15];
  const float* aW2 = (const float*)d_in[16];
  const float* ab2 = (const float*)d_in[17];
  const float* f1W = (const float*)d_in[18];
  const float* f1b = (const float*)d_in[19];
  const float* f2W = (const float*)d_in[20];
  const float* f2b = (const float*)d_in[21];

  u16* frag  = (u16*)d_ws;                          // 57344 B (W frags)
  float* bns = (float*)((char*)d_ws + 57344);       // 3584 B (folded BN)
  u16* afr   = (u16*)((char*)d_ws + 57344 + 3584);  // 12288 B (A frags)
  const int ngraphs = out_size / 7;

  prep<<<dim3(16), dim3(256), 0, stream>>>(cmW, clW, bng, bnb, bnm, bnv, frag, bns, afr);
  gcn_fused<<<dim3(ngraphs), dim3(256), 0, stream>>>(
      x, cfW, cfb, cmb, clb, aW1, ab1, aW2, ab2, f1W, f1b, f2W, f2b,
      frag, bns, afr, (float*)d_out);
}

// Round 9
// 156.816 us; speedup vs baseline: 1.4708x; 1.4708x over previous
//
#include <hip/hip_runtime.h>

typedef float f32x4 __attribute__((ext_vector_type(4)));
typedef float f32x2 __attribute__((ext_vector_type(2)));
typedef short short8 __attribute__((ext_vector_type(8)));
typedef unsigned int u32;
typedef unsigned short u16;

#define CLL 0.25f                     // landmark self/neighbor coeff (deg=4)
#define CML 0.06019292654288460f      // 0.5/sqrt(69)
#define SELFM 0.014492753623188406f   // 1/69

__device__ __forceinline__ u16 f2bf(float x) {
  u32 b = __float_as_uint(x);
  return (u16)((b + 0x7FFFu + ((b >> 16) & 1u)) >> 16);
}
__device__ __forceinline__ u32 cvtpk(float a, float b) {
  u32 r;
  asm("v_cvt_pk_bf16_f32 %0, %1, %2" : "=v"(r) : "v"(a), "v"(b));
  return r;
}
// packed f32 (VOP3P, CDNA full-rate): 2 values/lane per issue
__device__ __forceinline__ f32x2 pkadd(f32x2 a, f32x2 b) {
  f32x2 d;
  asm("v_pk_add_f32 %0, %1, %2" : "=v"(d) : "v"(a), "v"(b));
  return d;
}
__device__ __forceinline__ f32x2 pkfma(f32x2 a, f32x2 b, f32x2 c) {
  f32x2 d;
  asm("v_pk_fma_f32 %0, %1, %2, %3" : "=v"(d) : "v"(a), "v"(b), "v"(c));
  return d;
}

// prep: (a) swizzle 7 HIDxHID weight mats into bf16 MFMA B-fragments;
//       (b) fold BN into per-layer affine sc/sh.
__global__ void prep(const float* __restrict__ midW, const float* __restrict__ lastW,
                     const float* __restrict__ bng, const float* __restrict__ bnb,
                     const float* __restrict__ bnm, const float* __restrict__ bnv,
                     u16* __restrict__ frag, float* __restrict__ bns) {
  const int t0 = blockIdx.x * blockDim.x + threadIdx.x;
  for (int u = t0; u < 7 * 4 * 2 * 64; u += gridDim.x * blockDim.x) {
    const int lane = u & 63;
    const int t = u >> 6;
    const int ks = t & 1;
    const int nt = (t >> 1) & 3;
    const int l = t >> 3;  // 0..6 -> layers 1..7
    const float* W = (l < 6) ? (midW + l * 4096) : lastW;
    const int col = nt * 16 + (lane & 15);
    const int kb = ks * 32 + (lane >> 4) * 8;
    u16* dst = frag + (size_t)u * 8;
#pragma unroll
    for (int j = 0; j < 8; ++j) dst[j] = f2bf(W[(kb + j) * 64 + col]);
  }
  for (int u = t0; u < 7 * 64; u += gridDim.x * blockDim.x) {
    const int l = u >> 6, f = u & 63;
    const float sc = (float)((double)bng[l * 64 + f] / sqrt((double)bnv[l * 64 + f] + 1e-5));
    bns[l * 128 + f] = sc;
    bns[l * 128 + 64 + f] = bnb[l * 64 + f] - bnm[l * 64 + f] * sc;
  }
}

#define SUM4(V) ((V)[0] + (V)[1] + (V)[2] + (V)[3])
#define MAX4(V) fmaxf(fmaxf((V)[0], (V)[1]), fmaxf((V)[2], (V)[3]))
#define XY(V) ((f32x2){(V)[0], (V)[1]})
#define ZW(V) ((f32x2){(V)[2], (V)[3]})

// write address (elems) for node n=16*MT+4*qg+R, col c, XOR-swizzled
#define WADDR(MT, R) ((16 * (MT) + 4 * qg + (R)) * 64 + (cq ^ ((R) << 3)))

// ring stencil for one 4-node run; packed-f32 post-stencil chain.
#define STEP(MT, T, TPM1, TNP1, H, RESID)                              \
  {                                                                    \
    const float sp = (qg == 3) ? TPM1[3] : T[3];                       \
    const float pv = __shfl(sp, (lane + 48) & 63, 64);                 \
    const float sn = (qg == 0) ? TNP1[0] : T[0];                       \
    const float nv = __shfl(sn, (lane + 16) & 63, 64);                 \
    const float ta0 = ((MT) == 0 && qg == 0) ? t4[3] : pv;             \
    const float tb3 = ((MT) == 4 && qg == 0) ? t0[0] : nv;             \
    const float s01 = T[0] + T[1];                                     \
    const float s23 = T[2] + T[3];                                     \
    f32x2 oa = pkfma((f32x2){ta0 + s01, s01 + T[2]}, cll2, cmt2);      \
    f32x2 ob = pkfma((f32x2){T[1] + s23, s23 + tb3}, cll2, cmt2);      \
    oa = pkfma((f32x2){fmaxf(oa[0], 0.f), fmaxf(oa[1], 0.f)}, sc2, sh2); \
    ob = pkfma((f32x2){fmaxf(ob[0], 0.f), fmaxf(ob[1], 0.f)}, sc2, sh2); \
    if (RESID) {                                                       \
      oa = pkadd(oa, XY(H));                                           \
      ob = pkadd(ob, ZW(H));                                           \
    }                                                                  \
    H[0] = oa[0]; H[1] = oa[1]; H[2] = ob[0]; H[3] = ob[1];            \
  }

#define WPAIR(HW, MT, H)                                               \
  {                                                                    \
    const u32 pa = cvtpk(H[0], H[1]);                                  \
    const u32 pb = cvtpk(H[2], H[3]);                                  \
    (HW)[WADDR(MT, 0)] = (u16)pa;                                      \
    (HW)[WADDR(MT, 1)] = (u16)(pa >> 16);                              \
    (HW)[WADDR(MT, 2)] = (u16)pb;                                      \
    (HW)[WADDR(MT, 3)] = (u16)(pb >> 16);                              \
  }

// epilogue: master agg (packed sums) + stencil + bn/relu/resid, then bf16 writes
#define EPILOG(RESID, WRITE, HBW)                                      \
  {                                                                    \
    f32x2 qa = pkadd(pkadd(XY(t0), ZW(t0)), pkadd(XY(t1), ZW(t1)));    \
    f32x2 qb = pkadd(pkadd(XY(t2), ZW(t2)), pkadd(XY(t3), ZW(t3)));    \
    f32x2 qq = pkadd(pkadd(qa, qb), pkadd(XY(t4), ZW(t4)));            \
    float S = qq[0] + qq[1];                                           \
    if (qg == 1) S -= t4[0]; /* exclude master t; pad rows are 0 */    \
    S += __shfl_xor(S, 16, 64);                                        \
    S += __shfl_xor(S, 32, 64);                                        \
    const float t68b = __shfl(t4[0], 16 + p15, 64);                    \
    const float cmt = fmaf(CML, t68b, bias);                           \
    const f32x2 cll2 = {CLL, CLL};                                     \
    const f32x2 cmt2 = {cmt, cmt};                                     \
    const f32x2 sc2 = {sc, sc};                                        \
    const f32x2 sh2 = {sh, sh};                                        \
    float mv = fmaxf(fmaf(CML, S, fmaf(SELFM, t68b, bias)), 0.f);      \
    mv = fmaf(mv, sc, sh);                                             \
    if (RESID) mv += h4[0];                                            \
    STEP(0, t0, t4, t1, h0, RESID)                                     \
    STEP(1, t1, t0, t2, h1, RESID)                                     \
    STEP(2, t2, t1, t3, h2, RESID)                                     \
    STEP(3, t3, t2, t4, h3, RESID)                                     \
    STEP(4, t4, t3, t0, h4, RESID)                                     \
    if (qg == 1) h4[0] = mv; /* master h lives in slot [4][0] */       \
    if (WRITE) {                                                       \
      u16* hw_ = (HBW);                                                \
      WPAIR(hw_, 0, h0)                                                \
      WPAIR(hw_, 1, h1)                                                \
      WPAIR(hw_, 2, h2)                                                \
      WPAIR(hw_, 3, h3)                                                \
      if (qg == 0) { WPAIR(hw_, 4, h4) }                               \
      else if (qg == 1) hw_[68 * 64 + (c ^ 32)] = (u16)cvtpk(h4[0], h4[0]); \
    }                                                                  \
  }

#define MP(HR, MT, T)                                                  \
  {                                                                    \
    const short8 a0 = *(const short8*)&(HR)[(MT) * 1024 + ra0];        \
    const short8 a1 = *(const short8*)&(HR)[(MT) * 1024 + ra1];        \
    f32x4 acc = {0.f, 0.f, 0.f, 0.f};                                  \
    acc = __builtin_amdgcn_mfma_f32_16x16x32_bf16(a0, b0, acc, 0, 0, 0); \
    acc = __builtin_amdgcn_mfma_f32_16x16x32_bf16(a1, b1, acc, 0, 0, 0); \
    T = acc;                                                           \
  }

__launch_bounds__(256)
__global__ void gcn_fused(
    const float* __restrict__ x,
    const float* __restrict__ cfW, const float* __restrict__ cfb,
    const float* __restrict__ cmb, const float* __restrict__ clb,
    const float* __restrict__ aW1, const float* __restrict__ ab1,
    const float* __restrict__ aW2, const float* __restrict__ ab2,
    const float* __restrict__ f1W, const float* __restrict__ f1b,
    const float* __restrict__ f2W, const float* __restrict__ f2b,
    const u16* __restrict__ frag, const float* __restrict__ bns,
    float* __restrict__ out) {
  // LDS: 20480 + 1280 + 256 + 768 + 1024 = 23808 B
  __shared__ u16 hb[2][80 * 64];  // bf16 h double-buffer, rows 69..79 stay 0
  __shared__ float xl4[80 * 4];   // staged x, rows 69..79 = 0
  __shared__ float mrow[64];      // final master h
  __shared__ float gv[192];       // readout concat [mean|max|master*att]
  __shared__ float part[256];     // cross-wave partial buffer (att / fc1)

  const int tid = threadIdx.x;
  const int g = blockIdx.x;
  const int lane = tid & 63;
  const int wv = tid >> 6;
  const int p15 = lane & 15;
  const int qg = lane >> 4;
  const int c = wv * 16 + p15;            // this thread's feature column
  const int cq = c ^ ((qg & 1) << 5);     // write-swizzle base
  const int rsw = (p15 & 7) << 3;
  const int ra0 = (p15 * 64 + qg * 8) ^ rsw;        // A-frag kg=0 base
  const int ra1 = (p15 * 64 + 32 + qg * 8) ^ rsw;   // A-frag kg=1 base

  // ---- preload ALL per-layer scalars (hides global latency under staging)
  float lb[8], ls[8], lh[8];
  lb[0] = cfb[c]; ls[0] = bns[c]; lh[0] = bns[64 + c];
#pragma unroll
  for (int l = 1; l <= 6; ++l) {
    lb[l] = cmb[(l - 1) * 64 + c];
    ls[l] = bns[l * 128 + c];
    lh[l] = bns[l * 128 + 64 + c];
  }
  lb[7] = clb[c]; ls[7] = 1.f; lh[7] = 0.f;

  // prefetch layer-1 B fragments
  const u16* fb = frag + ((size_t)(0 * 4 + wv) * 2 * 64 + lane) * 8;
  short8 b0 = *(const short8*)fb;
  short8 b1 = *(const short8*)(fb + 512);

  // zero both hb buffers (pad rows must stay 0); stage x
  for (int i = tid; i < 5120; i += 256) ((u32*)hb)[i] = 0u;
  if (tid < 69)
    *(f32x4*)&xl4[tid * 4] = *(const f32x4*)&x[((size_t)g * 69 + tid) * 4];
  else if (tid < 80)
    *(f32x4*)&xl4[tid * 4] = (f32x4){0.f, 0.f, 0.f, 0.f};

  f32x4 t0, t1, t2, t3, t4;
  f32x4 h0, h1, h2, h3, h4;

  __syncthreads();

  // ---- layer 0: t = x @ W_first (exact fp32, K=4), nodes in MFMA layout
  {
    const float w0 = cfW[c], w1 = cfW[64 + c], w2 = cfW[128 + c], w3 = cfW[192 + c];
#define L0T(MT, T)                                                     \
    { _Pragma("unroll") for (int r = 0; r < 4; ++r) {                  \
        const f32x4 xv = *(const f32x4*)&xl4[(16 * (MT) + 4 * qg + r) * 4]; \
        T[r] = fmaf(xv[0], w0, fmaf(xv[1], w1, fmaf(xv[2], w2, xv[3] * w3))); } }
    L0T(0, t0) L0T(1, t1) L0T(2, t2) L0T(3, t3) L0T(4, t4)
#undef L0T
  }
  {
    const float bias = lb[0], sc = ls[0], sh = lh[0];
    EPILOG(false, true, &hb[0][0])
  }
  __syncthreads();

  // ---- layers 1..6: MFMA + packed register epilogue (bn + residual)
#pragma unroll
  for (int l = 1; l <= 6; ++l) {
    const u16* fbn = frag + ((size_t)(l * 4 + wv) * 2 * 64 + lane) * 8;
    const short8 nb0 = *(const short8*)fbn;
    const short8 nb1 = *(const short8*)(fbn + 512);
    const u16* hr = &hb[(l + 1) & 1][0];
    __builtin_amdgcn_s_setprio(1);
    MP(hr, 0, t0) MP(hr, 1, t1) MP(hr, 2, t2) MP(hr, 3, t3) MP(hr, 4, t4)
    __builtin_amdgcn_s_setprio(0);
    b0 = nb0;
    b1 = nb1;
    const float bias = lb[l], sc = ls[l], sh = lh[l];
    EPILOG(true, true, &hb[l & 1][0])
    __syncthreads();
  }

  // ---- layer 7: MFMA + epilogue (no bn, no residual, no hb write)
  {
    const u16* hr = &hb[0][0];
    __builtin_amdgcn_s_setprio(1);
    MP(hr, 0, t0) MP(hr, 1, t1) MP(hr, 2, t2) MP(hr, 3, t3) MP(hr, 4, t4)
    __builtin_amdgcn_s_setprio(0);
    const float bias = lb[7], sc = ls[7], sh = lh[7];
    EPILOG(false, false, (u16*)nullptr)
  }

  // ---- readout: per-col landmark mean/max from registers
  {
    float s = SUM4(h0) + SUM4(h1) + SUM4(h2) + SUM4(h3);
    float mx = fmaxf(fmaxf(MAX4(h0), MAX4(h1)), fmaxf(MAX4(h2), MAX4(h3)));
    if (qg == 0) {  // only qg==0's mt=4 run (nodes 64..67) is valid landmarks
      s += SUM4(h4);
      mx = fmaxf(mx, MAX4(h4));
    }
    s += __shfl_xor(s, 16, 64);
    s += __shfl_xor(s, 32, 64);
    mx = fmaxf(mx, __shfl_xor(mx, 16, 64));
    mx = fmaxf(mx, __shfl_xor(mx, 32, 64));
    if (qg == 0) {
      gv[c] = s * (1.f / 68.f);
      gv[64 + c] = mx;
    }
    if (qg == 1) mrow[c] = h4[0];
  }
  __syncthreads();

  // ---- attention gate (distributed over all 4 waves)
  {
    float z = 0.f;
#pragma unroll
    for (int k = 0; k < 16; ++k)
      z = fmaf(mrow[wv * 16 + k], aW1[(wv * 16 + k) * 64 + lane], z);
    part[wv * 64 + lane] = z;
  }
  __syncthreads();
  if (tid < 64) {
    float z = part[tid] + part[64 + tid] + part[128 + tid] + part[192 + tid] + ab1[tid];
    z = fmaxf(z, 0.f);
    float pr = z * aW2[tid];
#pragma unroll
    for (int off = 32; off > 0; off >>= 1) pr += __shfl_xor(pr, off, 64);
    const float att = 1.f / (1.f + expf(-(pr + ab2[0])));
    gv[128 + tid] = mrow[tid] * att;
  }
  __syncthreads();

  // ---- fc1 partials (distributed over all 4 waves)
  {
    float a = 0.f;
#pragma unroll
    for (int i = 0; i < 48; ++i)
      a = fmaf(gv[wv * 48 + i], f1W[(wv * 48 + i) * 64 + lane], a);
    part[wv * 64 + lane] = a;
  }
  __syncthreads();
  if (tid < 64) {
    float a = part[tid] + part[64 + tid] + part[128 + tid] + part[192 + tid] + f1b[tid];
    const float y = fmaxf(a, 0.f);
    float po[7];
#pragma unroll
    for (int o = 0; o < 7; ++o) po[o] = y * f2W[tid * 7 + o];
#pragma unroll
    for (int o = 0; o < 7; ++o)
#pragma unroll
      for (int off = 32; off > 0; off >>= 1) po[o] += __shfl_xor(po[o], off, 64);
    if (tid == 0) {
#pragma unroll
      for (int o = 0; o < 7; ++o) out[(size_t)g * 7 + o] = po[o] + f2b[o];
    }
  }
}

extern "C" void kernel_launch(void* const* d_in, const int* in_sizes, int n_in,
                              void* d_out, int out_size, void* d_ws, size_t ws_size,
                              hipStream_t stream) {
  (void)in_sizes; (void)n_in; (void)ws_size;
  const float* x   = (const float*)d_in[0];
  const float* cfW = (const float*)d_in[4];
  const float* cfb = (const float*)d_in[5];
  const float* cmW = (const float*)d_in[6];
  const float* cmb = (const float*)d_in[7];
  const float* clW = (const float*)d_in[8];
  const float* clb = (const float*)d_in[9];
  const float* bng = (const float*)d_in[10];
  const float* bnb = (const float*)d_in[11];
  const float* bnm = (const float*)d_in[12];
  const float* bnv = (const float*)d_in[13];
  const float* aW1 = (const float*)d_in[14];
  const float* ab1 = (const float*)d_in[15];
  const float* aW2 = (const float*)d_in[16];
  const float* ab2 = (const float*)d_in[17];
  const float* f1W = (const float*)d_in[18];
  const float* f1b = (const float*)d_in[19];
  const float* f2W = (const float*)d_in[20];
  const float* f2b = (const float*)d_in[21];

  u16* frag = (u16*)d_ws;                      // 57344 B
  float* bns = (float*)((char*)d_ws + 57344);  // 7*128 floats
  const int ngraphs = out_size / 7;

  prep<<<dim3(16), dim3(256), 0, stream>>>(cmW, clW, bng, bnb, bnm, bnv, frag, bns);
  gcn_fused<<<dim3(ngraphs), dim3(256), 0, stream>>>(
      x, cfW, cfb, cmb, clb, aW1, ab1, aW2, ab2, f1W, f1b, f2W, f2b,
      frag, bns, (float*)d_out);
}